// Round 4
// baseline (461.528 us; speedup 1.0000x reference)
//
#include <hip/hip_runtime.h>
#include <stdint.h>

// QuantConv1d: out[m][n] = (sum_k x[m][k]*w[k][n]) * scale[n] + bias[n]
// m=256, k=4096, n=16384. w arrives as int32 (harness-widened int8): 256 MiB stream.
//
// R1-R3 were serialization-bound: every __syncthreads emits s_waitcnt vmcnt(0)
// which drains the W prefetch queue each iteration (R3's occupancy doubling was
// exactly neutral; R1 ran at the same speed even with W fully L3-resident).
// R4: barrier-free, LDS-free. The 32x32x16 B-fragment (lane l = col n0+(l&31),
// k-octet (l>>5)*8+j) is loadable DIRECTLY with 8 row-strided dword loads per
// kstep (each instr: 2 rows x 128 B, fully coalesced). Waves are autonomous:
// 64m x 32n tile per wave (2 accs, 1 shared B-frag), 2-deep register pipeline,
// waits are precise per-register vmcnt — never a full drain.

typedef short bf16x8 __attribute__((ext_vector_type(8)));   // 8 bf16 = 16 B (MFMA A/B frag)
typedef float f32x16 __attribute__((ext_vector_type(16)));  // MFMA 32x32 accumulator
typedef unsigned short u16x4 __attribute__((ext_vector_type(4)));

#define K_DIM 4096
#define N_DIM 16384
#define KSTEPS 256         // K_DIM / 16 MFMA k-steps

__device__ __forceinline__ unsigned fbits(float f) {
  union { float f; unsigned u; } c; c.f = f; return c.u;
}
__device__ __forceinline__ unsigned short bf16rne(float f) {
  unsigned u = fbits(f);
  return (unsigned short)((u + 0x7FFFu + ((u >> 16) & 1u)) >> 16);
}

// ---------------- kernel 1: x fp32 -> bf16, A-fragment-major ----------------
// chunk c = (mt*256 + ks)*64 + lane holds A[m = mt*32 + (lane&31)]
//                                        [k = ks*16 + (lane>>5)*8 .. +8]  (16 B)
// => a wave's A-frag read for (mt, ks) is 64 contiguous 16 B chunks = 1 KiB.
__global__ __launch_bounds__(256) void cvt_x_frag(const float* __restrict__ x,
                                                  unsigned short* __restrict__ xb) {
  int c    = blockIdx.x * 256 + threadIdx.x;   // 131072 chunks
  int lane = c & 63;
  int ks   = (c >> 6) & 255;
  int mt   = c >> 14;
  int row  = mt * 32 + (lane & 31);
  int k0   = ks * 16 + (lane >> 5) * 8;
  const float4* p = (const float4*)(x + row * K_DIM + k0);
  float4 v0 = p[0], v1 = p[1];
  u16x4 o0, o1;
  o0.x = bf16rne(v0.x); o0.y = bf16rne(v0.y); o0.z = bf16rne(v0.z); o0.w = bf16rne(v0.w);
  o1.x = bf16rne(v1.x); o1.y = bf16rne(v1.y); o1.z = bf16rne(v1.z); o1.w = bf16rne(v1.w);
  u16x4* dst = (u16x4*)(xb + (size_t)c * 8);
  dst[0] = o0;
  dst[1] = o1;
}

// ---------------- kernel 2: GEMM, barrier-free ----------------
// block: 256 thr = 4 waves; wave wv owns m-tiles {2wv, 2wv+1} (64 rows) x the
// block's 32-column stripe. grid: 512 blocks; block bx owns cols [bx*32,+32)
// for ALL 256 rows => W fetched from HBM exactly once (L1 dedups the 4-wave
// intra-stripe reuse). No LDS, no __syncthreads anywhere.
__global__ __launch_bounds__(256, 4) void gemm_qconv(
    const unsigned short* __restrict__ xb,   // A-fragment-major bf16 (see cvt)
    const int* __restrict__ w,               // [4096][16384] int32
    const float* __restrict__ scale,
    const float* __restrict__ bias,
    float* __restrict__ out) {
  const int tid  = threadIdx.x;
  const int lane = tid & 63;
  const int wv   = tid >> 6;                 // 0..3
  const int l31  = lane & 31;
  const int half = lane >> 5;
  const int n0   = blockIdx.x * 32;

  // B-frag direct-load base: lane l covers col n0+l31, k-octet half*8+j
  const int* wlane = w + half * 8 * N_DIM + n0 + l31;

  // A-frag bases (16 B chunks), m-tiles 2wv and 2wv+1
  const bf16x8* af0 = (const bf16x8*)xb + (size_t)(2 * wv) * KSTEPS * 64 + lane;
  const bf16x8* af1 = af0 + (size_t)KSTEPS * 64;

  int    Wr[2][8];
  bf16x8 A0[2], A1[2];
  f32x16 acc0 = {}, acc1 = {};

  // 2-deep pipeline: batch p = {8 W dwords, 2 A dwordx4}; while batch p is
  // being consumed (vmcnt waits on ITS registers only), batch p^1 stays in
  // flight — no barrier ever drains the queue.
#define LOAD_BATCH(p, s)                                              \
  {                                                                   \
    const int* wp_ = wlane + (s) * 16 * N_DIM;                        \
    _Pragma("unroll")                                                 \
    for (int j = 0; j < 8; ++j) Wr[p][j] = wp_[j * N_DIM];            \
    A0[p] = af0[(s) * 64];                                            \
    A1[p] = af1[(s) * 64];                                            \
  }

  LOAD_BATCH(0, 0)
  LOAD_BATCH(1, 1)

#pragma unroll 1
  for (int s = 0; s < KSTEPS; s += 2) {
#pragma unroll
    for (int h = 0; h < 2; ++h) {
      // int32 -> bf16 pack (exact: |w|<=128): consecutive-k pairs per dword
      int ch[4];
#pragma unroll
      for (int d = 0; d < 4; ++d) {
        float a0 = (float)Wr[h][2 * d];
        float a1 = (float)Wr[h][2 * d + 1];
        ch[d] = (int)__builtin_amdgcn_perm(fbits(a1), fbits(a0), 0x07060302u);
      }
      bf16x8 b = *(const bf16x8*)ch;
      acc0 = __builtin_amdgcn_mfma_f32_32x32x16_bf16(A0[h], b, acc0, 0, 0, 0);
      acc1 = __builtin_amdgcn_mfma_f32_32x32x16_bf16(A1[h], b, acc1, 0, 0, 0);
      const int sn = s + 2 + h;
      if (sn < KSTEPS) LOAD_BATCH(h, sn)   // wave-uniform branch
    }
  }

  // epilogue: C/D map col=lane&31, row=(reg&3)+8*(reg>>2)+4*(lane>>5)
  const int n = n0 + l31;
  const float sc = scale[n];
  const float bs = bias[n];
#pragma unroll
  for (int r = 0; r < 2; ++r) {
    const f32x16 acc = r ? acc1 : acc0;
#pragma unroll
    for (int g = 0; g < 16; ++g) {
      const int m = (2 * wv + r) * 32 + (g & 3) + 8 * (g >> 2) + 4 * half;
      out[m * N_DIM + n] = acc[g] * sc + bs;
    }
  }
}

extern "C" void kernel_launch(void* const* d_in, const int* in_sizes, int n_in,
                              void* d_out, int out_size, void* d_ws, size_t ws_size,
                              hipStream_t stream) {
  const float* x     = (const float*)d_in[0];   // [8,32,4096] fp32
  const int*   wgt   = (const int*)d_in[1];     // [4096,16384] int32
  const float* scale = (const float*)d_in[2];   // [1,16384]
  const float* bias  = (const float*)d_in[3];   // [16384]
  float* out = (float*)d_out;
  unsigned short* xb = (unsigned short*)d_ws;   // 2 MiB fragment-major bf16 x

  cvt_x_frag<<<512, 256, 0, stream>>>(x, xb);
  gemm_qconv<<<N_DIM / 32, 256, 0, stream>>>(xb, wgt, scale, bias, out);
}

// Round 5
// 413.622 us; speedup vs baseline: 1.1158x; 1.1158x over previous
//
#include <hip/hip_runtime.h>
#include <stdint.h>

// QuantConv1d: out[m][n] = (sum_k x[m][k]*w[k][n]) * scale[n] + bias[n]
// m=256, k=4096, n=16384. w arrives as int32 (harness-widened int8): 256 MiB stream.
//
// R1-R4 all plateaued at ~200us gemm regardless of structure (even W-in-L3):
// conditional prefetches make outstanding-load counts branch-dependent, forcing
// the compiler to emit vmcnt(0) full drains at every consume -> serial latency
// per kstep. R5 ports the proven m97 skeleton: async global_load_lds for W
// (no dest registers -> no register waits; the only drain is the per-iter
// barrier, issued a full compute-phase after the DMA), double-buffered LDS,
// ONE barrier/iter, all loads unconditional (last-iter DMA wraps to k=0).

typedef short bf16x8 __attribute__((ext_vector_type(8)));   // 8 bf16 = 16 B (MFMA A/B frag)
typedef float f32x16 __attribute__((ext_vector_type(16)));  // MFMA 32x32 accumulator
typedef unsigned short u16x4 __attribute__((ext_vector_type(4)));

#define K_DIM 4096
#define N_DIM 16384
#define BK 64
#define BN 32
#define NIT (K_DIM / BK)   // 64 iterations
#define KSTEPS 256         // K_DIM / 16 MFMA k-steps (4 per iteration)

__device__ __forceinline__ unsigned fbits(float f) {
  union { float f; unsigned u; } c; c.f = f; return c.u;
}
__device__ __forceinline__ unsigned short bf16rne(float f) {
  unsigned u = fbits(f);
  return (unsigned short)((u + 0x7FFFu + ((u >> 16) & 1u)) >> 16);
}
__device__ __forceinline__ void load_lds16(const int* g, void* l) {
  __builtin_amdgcn_global_load_lds(
      (const __attribute__((address_space(1))) void*)g,
      (__attribute__((address_space(3))) void*)l, 16, 0, 0);
}

// ---------------- kernel 1: x fp32 -> bf16, A-fragment-major ----------------
// chunk c = (mt*256 + ks)*64 + lane holds A[m = mt*32 + (lane&31)]
//                                        [k = ks*16 + (lane>>5)*8 .. +8]  (16 B)
// => a wave's A-frag read for (mt, ks) is 64 contiguous 16 B chunks = 1 KiB.
__global__ __launch_bounds__(256) void cvt_x_frag(const float* __restrict__ x,
                                                  unsigned short* __restrict__ xb) {
  int c    = blockIdx.x * 256 + threadIdx.x;   // 131072 chunks
  int lane = c & 63;
  int ks   = (c >> 6) & 255;
  int mt   = c >> 14;
  int row  = mt * 32 + (lane & 31);
  int k0   = ks * 16 + (lane >> 5) * 8;
  const float4* p = (const float4*)(x + row * K_DIM + k0);
  float4 v0 = p[0], v1 = p[1];
  u16x4 o0, o1;
  o0.x = bf16rne(v0.x); o0.y = bf16rne(v0.y); o0.z = bf16rne(v0.z); o0.w = bf16rne(v0.w);
  o1.x = bf16rne(v1.x); o1.y = bf16rne(v1.y); o1.z = bf16rne(v1.z); o1.w = bf16rne(v1.w);
  u16x4* dst = (u16x4*)(xb + (size_t)c * 8);
  dst[0] = o0;
  dst[1] = o1;
}

// ---------------- kernel 2: GEMM, m97-style async-LDS pipeline ----------------
// 256 thr = 4 waves; wave wv owns m-tiles {2wv, 2wv+1} (64 rows) x the block's
// 32-col stripe. grid 512 (2 blocks/CU); block bx owns cols [32bx, 32bx+32)
// for ALL 256 rows => W fetched exactly once. W tile (64k x 32n int32, 8 KiB)
// is DMA'd row-major into LDS; the column-strided ds_read_b32s ARE the
// k-transpose (bank = col%32 -> conflict-free).
__global__ __launch_bounds__(256, 2) void gemm_qconv(
    const unsigned short* __restrict__ xb,   // A-fragment-major bf16 (see cvt)
    const int* __restrict__ w,               // [4096][16384] int32
    const float* __restrict__ scale,
    const float* __restrict__ bias,
    float* __restrict__ out) {
  __shared__ int Wlds[2][BK * BN];           // 2 x 8 KiB, [k][n] row-major

  const int tid  = threadIdx.x;
  const int lane = tid & 63;
  const int wv   = tid >> 6;                 // 0..3
  const int l31  = lane & 31;
  const int half = lane >> 5;
  const int n0   = blockIdx.x * BN;

  // DMA assignment: instr i (0..7) covers W rows [8i, 8i+8) of the tile;
  // wave wv issues i = 2wv, 2wv+1. lane l -> row 8i + (l>>3), col ints 4*(l&7).
  // LDS dest: uniform base + lane*16 => row-major [64][32] contiguous. 1 KiB/instr.
  const int i0 = 2 * wv;
  const int* gdma = w + (i0 * 8 + (lane >> 3)) * N_DIM + n0 + 4 * (lane & 7);

  // A-fragment bases (16 B chunks): m-tiles 2wv and 2wv+1
  const bf16x8* af0 = (const bf16x8*)xb + (size_t)(2 * wv) * KSTEPS * 64 + lane;
  const bf16x8* af1 = af0 + (size_t)KSTEPS * 64;

  f32x16 acc0 = {}, acc1 = {};

  // prologue: DMA tile 0 into buf 0, drain at barrier
  load_lds16(gdma, &Wlds[0][i0 * 256]);
  load_lds16(gdma + 8 * N_DIM, &Wlds[0][i0 * 256 + 256]);
  __syncthreads();

#pragma unroll 1
  for (int it = 0; it < NIT; ++it) {
    const int buf = it & 1;

    // A-frags for THIS iter first (oldest in vmcnt queue: waiting on them
    // never drains the DMAs issued below)
    bf16x8 A0[4], A1[4];
#pragma unroll
    for (int s = 0; s < 4; ++s) {
      A0[s] = af0[(it * 4 + s) * 64];
      A1[s] = af1[(it * 4 + s) * 64];
    }

    // async DMA of NEXT tile into buf^1 — UNCONDITIONAL (wraps to k=0 on the
    // last iter: harmless garbage into the dead buffer, keeps vmcnt static)
    {
      const int knext = (it + 1 == NIT) ? 0 : (it + 1) * BK;
      const int* g = gdma + knext * N_DIM;
      load_lds16(g, &Wlds[buf ^ 1][i0 * 256]);
      load_lds16(g + 8 * N_DIM, &Wlds[buf ^ 1][i0 * 256 + 256]);
    }

    // compute tile `it` from buf: 4 ksteps; B-frag = 8 column-strided ints
#pragma unroll
    for (int s = 0; s < 4; ++s) {
      int bi[8];
#pragma unroll
      for (int j = 0; j < 8; ++j)
        bi[j] = Wlds[buf][(16 * s + 8 * half + j) * BN + l31];
      int ch[4];
#pragma unroll
      for (int d = 0; d < 4; ++d) {
        float a0 = (float)bi[2 * d];
        float a1 = (float)bi[2 * d + 1];
        ch[d] = (int)__builtin_amdgcn_perm(fbits(a1), fbits(a0), 0x07060302u);
      }
      bf16x8 b = *(const bf16x8*)ch;
      acc0 = __builtin_amdgcn_mfma_f32_32x32x16_bf16(A0[s], b, acc0, 0, 0, 0);
      acc1 = __builtin_amdgcn_mfma_f32_32x32x16_bf16(A1[s], b, acc1, 0, 0, 0);
    }

    // ONE barrier: drains this iter's DMAs (issued ~a full compute phase ago,
    // so already complete) and fences buf reuse.
    __syncthreads();
  }

  // epilogue: C/D map col=lane&31, row=(reg&3)+8*(reg>>2)+4*(lane>>5)
  const int n = n0 + l31;
  const float sc = scale[n];
  const float bs = bias[n];
#pragma unroll
  for (int r = 0; r < 2; ++r) {
    const f32x16 acc = r ? acc1 : acc0;
#pragma unroll
    for (int g = 0; g < 16; ++g) {
      const int m = (2 * wv + r) * 32 + (g & 3) + 8 * (g >> 2) + 4 * half;
      out[m * N_DIM + n] = acc[g] * sc + bs;
    }
  }
}

extern "C" void kernel_launch(void* const* d_in, const int* in_sizes, int n_in,
                              void* d_out, int out_size, void* d_ws, size_t ws_size,
                              hipStream_t stream) {
  const float* x     = (const float*)d_in[0];   // [8,32,4096] fp32
  const int*   wgt   = (const int*)d_in[1];     // [4096,16384] int32
  const float* scale = (const float*)d_in[2];   // [1,16384]
  const float* bias  = (const float*)d_in[3];   // [16384]
  float* out = (float*)d_out;
  unsigned short* xb = (unsigned short*)d_ws;   // 2 MiB fragment-major bf16 x

  cvt_x_frag<<<512, 256, 0, stream>>>(x, xb);
  gemm_qconv<<<N_DIM / BN, 256, 0, stream>>>(xb, wgt, scale, bias, out);
}